// Round 3
// baseline (216.780 us; speedup 1.0000x reference)
//
#include <hip/hip_runtime.h>
#include <math.h>

#define N 4096
#define IN_F 256
#define OUT_F 512
#define H 8
#define D 64
#define NEG 0.2f
#define JC 1024            // j-chunk per block (4 chunks)
#define LOG2E 1.44269504f

typedef __attribute__((ext_vector_type(8))) short bf16x8;
typedef __attribute__((ext_vector_type(4))) float f32x4;

__device__ __forceinline__ float leaky(float x) { return fmaxf(x, NEG * x); }

__device__ __forceinline__ unsigned short f2bf(float x) {
    union { float f; unsigned u; } v; v.f = x;
    unsigned r = v.u + 0x7fff + ((v.u >> 16) & 1);  // RNE
    return (unsigned short)(r >> 16);
}

// monotone float<->uint map for atomicMax-based float max
__device__ __forceinline__ unsigned fmap(float x) {
    union { float f; unsigned u; } v; v.f = x;
    return (v.u & 0x80000000u) ? ~v.u : (v.u | 0x80000000u);
}
__device__ __forceinline__ float funmap(unsigned m) {
    union { float f; unsigned u; } v;
    v.u = (m & 0x80000000u) ? (m & 0x7fffffffu) : ~m;
    return v.f;
}

// async 16B global->LDS DMA
__device__ __forceinline__ void dma16(const void* g, void* l) {
    __builtin_amdgcn_global_load_lds((const __attribute__((address_space(1))) void*)g,
                                     (__attribute__((address_space(3))) void*)l, 16, 0, 0);
}

// ---- K1: h = inp @ W^T per (i-tile, head). BK=64, register-prefetch double buffer.
// Epilogue: scores s + block-reduced smax + bf16 transpose to hbT[h][d][j].
__global__ __launch_bounds__(256) void k_gemm(const float* __restrict__ inp,
                                              const float* __restrict__ W,
                                              const float* __restrict__ a_left,
                                              unsigned short* __restrict__ hbT,
                                              float* __restrict__ s,
                                              unsigned* __restrict__ smaxU) {
    __shared__ float As[64][68];  // [k][i] 17.4 KB
    __shared__ float Bs[64][68];  // [k][o] 17.4 KB
    __shared__ unsigned short h_st[64][72];
    __shared__ float s_red[64];

    const int t = threadIdx.x;
    const int bi = blockIdx.x;
    const int head = blockIdx.y;
    const int ty = t >> 4, tx = t & 15;
    const int lr = t >> 2;            // 0..63 row within tile
    const int cq = (t & 3) * 16;      // k sub-offset

    float4 pa[4], pb[4];
    auto loadrk = [&](int k0) {
        const float* ip = &inp[(size_t)(bi * 64 + lr) * IN_F + k0 + cq];
        const float* wp = &W[(size_t)(head * 64 + lr) * IN_F + k0 + cq];
#pragma unroll
        for (int q = 0; q < 4; ++q) {
            pa[q] = *(const float4*)&ip[q * 4];
            pb[q] = *(const float4*)&wp[q * 4];
        }
    };
    loadrk(0);

    float acc[4][4] = {};
    for (int k0 = 0; k0 < IN_F; k0 += 64) {
        __syncthreads();
#pragma unroll
        for (int q = 0; q < 4; ++q)
#pragma unroll
            for (int j = 0; j < 4; ++j) {
                As[cq + q * 4 + j][lr] = ((const float*)&pa[q])[j];
                Bs[cq + q * 4 + j][lr] = ((const float*)&pb[q])[j];
            }
        __syncthreads();
        if (k0 + 64 < IN_F) loadrk(k0 + 64);  // prefetch next slice, hidden by compute
#pragma unroll
        for (int k = 0; k < 64; ++k) {
            float4 a4 = *(const float4*)&As[k][ty * 4];
            float4 b4 = *(const float4*)&Bs[k][tx * 4];
            float a[4] = {a4.x, a4.y, a4.z, a4.w};
            float b[4] = {b4.x, b4.y, b4.z, b4.w};
#pragma unroll
            for (int r = 0; r < 4; ++r)
#pragma unroll
                for (int c = 0; c < 4; ++c) acc[r][c] = fmaf(a[r], b[c], acc[r][c]);
        }
    }

    // scores: s[head][i] = sum_d h[i][d]*a_left[head][d]
    float aL[4];
#pragma unroll
    for (int c = 0; c < 4; ++c) aL[c] = a_left[head * D + tx * 4 + c];
#pragma unroll
    for (int r = 0; r < 4; ++r) {
        float sp = acc[r][0] * aL[0] + acc[r][1] * aL[1] + acc[r][2] * aL[2] + acc[r][3] * aL[3];
        sp += __shfl_xor(sp, 1); sp += __shfl_xor(sp, 2);
        sp += __shfl_xor(sp, 4); sp += __shfl_xor(sp, 8);
        if (tx == 0) {
            s[head * N + bi * 64 + ty * 4 + r] = sp;
            s_red[ty * 4 + r] = sp;
        }
    }
    __syncthreads();
    if (t < 64) {  // block-level max -> ONE atomic per block
        float m = s_red[t];
        for (int off = 32; off; off >>= 1) m = fmaxf(m, __shfl_down(m, off, 64));
        if (t == 0) atomicMax(&smaxU[head], fmap(m));
    }

    // stage h tile as bf16 and transpose to hbT[head][d][i]
#pragma unroll
    for (int r = 0; r < 4; ++r) {
        ushort4 v;
        v.x = f2bf(acc[r][0]); v.y = f2bf(acc[r][1]);
        v.z = f2bf(acc[r][2]); v.w = f2bf(acc[r][3]);
        *(ushort4*)&h_st[ty * 4 + r][tx * 4] = v;
    }
    __syncthreads();
    {
        const int d = t >> 2, iq = (t & 3) * 16;
        unsigned short us[16];
#pragma unroll
        for (int k = 0; k < 16; ++k) us[k] = h_st[iq + k][d];
        unsigned short* dst = &hbT[((size_t)(head * D + d)) * N + bi * 64 + iq];
#pragma unroll
        for (int q = 0; q < 4; ++q) {
            ushort4 v = {us[q * 4 + 0], us[q * 4 + 1], us[q * 4 + 2], us[q * 4 + 3]};
            *(ushort4*)&dst[q * 4] = v;
        }
    }
}

// ---- K2: per-row max of A
__global__ __launch_bounds__(256) void k_rowmax(const float* __restrict__ A,
                                                float* __restrict__ rmax) {
    int i = blockIdx.x;
    const float* row = &A[(size_t)i * N];
    float m = -1e30f;
    for (int j = threadIdx.x * 4; j < N; j += 256 * 4) {
        float4 v = *(const float4*)&row[j];
        m = fmaxf(fmaxf(fmaxf(m, v.x), fmaxf(v.y, v.z)), v.w);
    }
    for (int off = 32; off; off >>= 1) m = fmaxf(m, __shfl_down(m, off, 64));
    __shared__ float red[4];
    if ((threadIdx.x & 63) == 0) red[threadIdx.x >> 6] = m;
    __syncthreads();
    if (threadIdx.x == 0) rmax[i] = fmaxf(fmaxf(red[0], red[1]), fmaxf(red[2], red[3]));
}

// ---- K3: fused attention, HEAD-SHARED A.
// Block = 512 thr (8 waves): waves 0-3 -> heads 0-3, waves 4-7 -> heads 4-7;
// each wave owns 16 i-rows (wg) x 64 d x its 4 heads over a JC j-chunk.
// Per 32-j step: double-buffered DMA of A tile (64x32 f32) + hbT tile
// (8h x 64d x 32j bf16), both XOR-swizzled via pre-swizzled SOURCE address
// (global_load_lds dest must stay linear), prefetched 1 step ahead.
// NOTE r3: v_cvt_pk_bf16_f32 asm reverted to baseline-verified f2bf manual
// pack — bisecting the round-2 absmax failure (pack order was the prime
// unverified suspect; all data paths re-audited clean vs the 197us baseline).
__global__ __launch_bounds__(512, 2) void k_attn(const float* __restrict__ A,
                                                 const unsigned short* __restrict__ hbT,
                                                 const float* __restrict__ s,
                                                 const unsigned* __restrict__ smaxU,
                                                 const float* __restrict__ rmax,
                                                 float* __restrict__ out,
                                                 float* __restrict__ Z) {
    __shared__ float A_st[2][2048];             // 2 x 8KB  (64 rows x 32 j)
    __shared__ unsigned short hT_st[2][16384];  // 2 x 32KB (512 rows x 32 j)
    __shared__ float s_ch[8 * JC];              // 32KB, pre-scaled by log2(e)

    const int t = threadIdx.x;
    // XCD-aware decode: consecutive linear ids (round-robin over 8 XCDs) keep the
    // same j-chunk on the same XCD pair -> hbT chunk (1MB) stays L2-resident.
    const int bid = blockIdx.x;
    const int k8 = bid & 7;
    const int jcid = k8 >> 1;
    const int itile = (bid >> 3) + ((k8 & 1) << 5);
    const int i0 = itile * 64;
    const int j0 = jcid * JC;

    const int lane = t & 63, wave = t >> 6;
    const int quad = lane >> 4, li = lane & 15;
    const int wg = wave & 3, hg = wave >> 2;
    const int myrow = i0 + wg * 16 + li;

    // stage s chunk, pre-scaled by log2(e): 16 floats per thread
#pragma unroll
    for (int q = 0; q < 4; ++q) {
        int idx = (q * 512 + t) * 4;
        int hh = idx >> 10;          // / JC
        int jj = idx & (JC - 1);
        float4 v = *(const float4*)&s[hh * N + j0 + jj];
        v.x *= LOG2E; v.y *= LOG2E; v.z *= LOG2E; v.w *= LOG2E;
        *(float4*)&s_ch[idx] = v;
    }

    // per-head scaled score + softmax upper bound (all in exp2 domain)
    const float rmv = rmax[myrow];
    float sI[4], mb[4];
#pragma unroll
    for (int h = 0; h < 4; ++h) {
        int ha = hg * 4 + h;
        float sr = s[ha * N + myrow];
        float sm = funmap(smaxU[ha]);
        float x = sr + sm;
        mb[h] = (leaky(x) + rmv) * LOG2E;
        sI[h] = sr * LOG2E;
    }

    // DMA source pointers, pre-swizzled so the linear LDS dest yields a
    // bank-conflict-free read layout (rule: swizzle both-sides-or-neither).
    // A: LDS slot (r*8+c) holds A[r][ (c^(r&7))*4 .. +3 ]
    const int ar = t >> 3, ac = t & 7;
    const float* gA = &A[(size_t)(i0 + ar) * N + j0 + ((ac ^ (ar & 7)) * 4)];
    // hbT: LDS slot (R*4+sl) holds hbT[R][ (sl^((R>>1)&3))*8 .. +7 ]
    const unsigned short* gH[4];
#pragma unroll
    for (int q = 0; q < 4; ++q) {
        int m = q * 512 + t, R = m >> 2, sl = m & 3;
        gH[q] = &hbT[(size_t)R * N + j0 + ((sl ^ ((R >> 1) & 3)) * 8)];
    }

    // prologue: stage step 0 into buffer 0
    dma16(gA, &A_st[0][t * 4]);
#pragma unroll
    for (int q = 0; q < 4; ++q) dma16(gH[q], &hT_st[0][(q * 512 + t) * 8]);
    __syncthreads();

    f32x4 acc[4][4] = {{{0,0,0,0}},{{0,0,0,0}},{{0,0,0,0}},{{0,0,0,0}}};
    float zs[4] = {0.f, 0.f, 0.f, 0.f};

    const int arow = wg * 16 + li;
    const int sw0 = (quad * 2) ^ (arow & 7);
    const int sw1 = (quad * 2 + 1) ^ (arow & 7);
    const int hsw = quad ^ ((li >> 1) & 3);  // per-lane constant hbT read swizzle

#pragma unroll 2
    for (int it = 0; it < JC / 32; ++it) {
        const int cur = it & 1;
        // prefetch next step (lands during this step's compute; drained at the barrier)
        if (it + 1 < JC / 32) {
            const int jn = (it + 1) * 32;
            dma16(gA + jn, &A_st[cur ^ 1][t * 4]);
#pragma unroll
            for (int q = 0; q < 4; ++q)
                dma16(gH[q] + jn, &hT_st[cur ^ 1][(q * 512 + t) * 8]);
        }
        const float* bA = A_st[cur];
        const unsigned short* bH = hT_st[cur];
        const int jt = it * 32;

        // A values for this lane's row / j-slice, scaled once, shared by 4 heads
        float4 a0 = *(const float4*)&bA[(arow * 8 + sw0) * 4];
        float4 a1 = *(const float4*)&bA[(arow * 8 + sw1) * 4];
        float av[8] = {a0.x, a0.y, a0.z, a0.w, a1.x, a1.y, a1.z, a1.w};
#pragma unroll
        for (int p = 0; p < 8; ++p) av[p] *= LOG2E;

#pragma unroll
        for (int h = 0; h < 4; ++h) {
            const int ha = hg * 4 + h;
            float4 s0 = *(const float4*)&s_ch[ha * JC + jt + quad * 8];
            float4 s1 = *(const float4*)&s_ch[ha * JC + jt + quad * 8 + 4];
            float sv[8] = {s0.x, s0.y, s0.z, s0.w, s1.x, s1.y, s1.z, s1.w};
            union { bf16x8 v; unsigned u[4]; } P;
#pragma unroll
            for (int p = 0; p < 4; ++p) {
                float x0 = sI[h] + sv[2 * p + 0];
                float x1 = sI[h] + sv[2 * p + 1];
                float w0 = __builtin_amdgcn_exp2f(fmaxf(x0, NEG * x0) - mb[h] + av[2 * p + 0]);
                float w1 = __builtin_amdgcn_exp2f(fmaxf(x1, NEG * x1) - mb[h] + av[2 * p + 1]);
                zs[h] += w0 + w1;
                P.u[p] = ((unsigned)f2bf(w1) << 16) | (unsigned)f2bf(w0);  // lo=w0 (j even)
            }
#pragma unroll
            for (int db = 0; db < 4; ++db) {
                const int R = ha * 64 + db * 16 + li;
                bf16x8 hf = *(const bf16x8*)&bH[(R * 4 + hsw) * 8];
                acc[h][db] = __builtin_amdgcn_mfma_f32_16x16x32_bf16(P.v, hf, acc[h][db], 0, 0, 0);
            }
        }
        __syncthreads();
    }

    // Z: reduce each head's partial over the 4 quads of the wave
#pragma unroll
    for (int h = 0; h < 4; ++h) {
        float z = zs[h];
        z += __shfl_xor(z, 16);
        z += __shfl_xor(z, 32);
        if (quad == 0) atomicAdd(&Z[(hg * 4 + h) * N + myrow], z);
    }

    // out: C layout row = quad*4+r, col = li
#pragma unroll
    for (int h = 0; h < 4; ++h) {
#pragma unroll
        for (int r = 0; r < 4; ++r) {
            float* op = &out[(size_t)(i0 + wg * 16 + quad * 4 + r) * OUT_F + (hg * 4 + h) * D];
#pragma unroll
            for (int db = 0; db < 4; ++db) atomicAdd(&op[db * 16 + li], acc[h][db][r]);
        }
    }
}

// ---- K4: normalize
__global__ __launch_bounds__(256) void k_norm(float* __restrict__ out,
                                              const float* __restrict__ Z) {
    int idx = blockIdx.x * 256 + threadIdx.x;
    int i = idx >> 9, hd = idx & 511, hh = hd >> 6;
    out[idx] = out[idx] / Z[hh * N + i];
}

extern "C" void kernel_launch(void* const* d_in, const int* in_sizes, int n_in,
                              void* d_out, int out_size, void* d_ws, size_t ws_size,
                              hipStream_t stream) {
    const float* inp = (const float*)d_in[0];
    const float* A = (const float*)d_in[1];
    const float* W = (const float*)d_in[2];
    const float* a_left = (const float*)d_in[3];
    float* out = (float*)d_out;

    // ws layout: hbT (4MB) | s (128KB) | Z (128KB) | smaxU (32B) | rmax (16KB)
    unsigned short* hbT = (unsigned short*)d_ws;
    float* s = (float*)((char*)d_ws + (size_t)H * D * N * 2);
    float* Z = s + (size_t)H * N;
    unsigned* smaxU = (unsigned*)(Z + (size_t)H * N);
    float* rmax = (float*)(smaxU + 8);

    hipMemsetAsync(out, 0, (size_t)N * OUT_F * sizeof(float), stream);
    hipMemsetAsync(Z, 0, (size_t)H * N * sizeof(float) + 8 * sizeof(unsigned), stream);

    k_gemm<<<dim3(N / 64, H), 256, 0, stream>>>(inp, W, a_left, hbT, s, smaxU);
    k_rowmax<<<dim3(N), 256, 0, stream>>>(A, rmax);
    k_attn<<<dim3(256), 512, 0, stream>>>(A, hbT, s, smaxU, rmax, out, Z);
    k_norm<<<dim3(N * OUT_F / 256), 256, 0, stream>>>(out, Z);
}